// Round 8
// baseline (519.991 us; speedup 1.0000x reference)
//
#include <hip/hip_runtime.h>
#include <hip/hip_bf16.h>

#define NEDGE 262144
#define DIM 256
#define NNODE 50000
#define NLAYER 3
#define EPSV 1e-5f

#define GBM 512                 // rows per GEMM block
#define RC 64                   // rows per chunk
#define NCH (GBM / RC)          // 8 chunks per block
#define GEMM_GRID (NEDGE / GBM) // 512 blocks

typedef __attribute__((ext_vector_type(8))) short bf16x8_t;
typedef __attribute__((ext_vector_type(4))) float f32x4_t;

__device__ __forceinline__ float bf2f(short s) {
  unsigned u = ((unsigned)(unsigned short)s) << 16;
  return __builtin_bit_cast(float, u);
}
__device__ __forceinline__ short f2bf(float f) {
  __hip_bfloat16 h = __float2bfloat16(f);
  return __builtin_bit_cast(short, h);
}

// ---------------- Kernel 0a: convert Ws (fp32) -> bf16 ----------------
extern "C" __global__ void __launch_bounds__(256)
k_cvt(const float* __restrict__ src, short* __restrict__ dst, int n) {
  int i = blockIdx.x * 256 + threadIdx.x;
  if (i < n) dst[i] = f2bf(src[i]);
}

// ---------------- Kernel 0b: convert x (fp32) -> bf16, 8 elems/thread -------
extern "C" __global__ void __launch_bounds__(256)
k_cvt_x(const float* __restrict__ src, short* __restrict__ dst, int n8) {
  int i = blockIdx.x * 256 + threadIdx.x;
  if (i >= n8) return;
  const float4 a = *(const float4*)(src + (size_t)i * 8);
  const float4 b = *(const float4*)(src + (size_t)i * 8 + 4);
  bf16x8_t o;
  o[0] = f2bf(a.x); o[1] = f2bf(a.y); o[2] = f2bf(a.z); o[3] = f2bf(a.w);
  o[4] = f2bf(b.x); o[5] = f2bf(b.y); o[6] = f2bf(b.z); o[7] = f2bf(b.w);
  *(bf16x8_t*)(dst + (size_t)i * 8) = o;
}

// ======== Kernel 1: FUSED gather+LN+GEMM1:  C = LN(xb[s]+xb[d]) @ W^T ========
// 8 waves x 512 threads; wave w owns cols [w*32,+32), W in 64 VGPRs.
// 2-deep reg-staged gather prefetch (loads fly across compute; forced complete
// at the __syncthreads drain -- proven-safe R5 structure).
// C-stores NON-TEMPORAL so the 128MB stream doesn't evict xb from L3.
extern "C" __global__ void __launch_bounds__(512)
k_gemm1f(const short* __restrict__ xb, const int* __restrict__ ei,
         const float* __restrict__ lnw, const short* __restrict__ W,
         short* __restrict__ C, float* __restrict__ psum, float* __restrict__ psq) {
  __shared__ short As[2][RC * DIM];  // 2 x 32 KB
  __shared__ int sIdx[GBM], dIdx[GBM];
  const int tid = threadIdx.x;
  const int w = tid >> 6;
  const int lane = tid & 63;
  const int rl = lane & 15;
  const int kh = lane >> 4;
  const int row0 = blockIdx.x * GBM;
  const int colbase = w * 32;
  const int cst = tid & 31;

  sIdx[tid] = ei[row0 + tid];
  dIdx[tid] = ei[NEDGE + row0 + tid];

  bf16x8_t wf[2][8];
#pragma unroll
  for (int n = 0; n < 2; ++n)
#pragma unroll
    for (int ks = 0; ks < 8; ++ks)
      wf[n][ks] = *(const bf16x8_t*)(W + (size_t)(colbase + n * 16 + rl) * DIM + ks * 32 + kh * 8);

  float lw[8];
#pragma unroll
  for (int j = 0; j < 8; ++j) lw[j] = lnw[cst * 8 + j];

  float st_s0 = 0.f, st_s1 = 0.f, st_q0 = 0.f, st_q1 = 0.f;

  // two named staging sets (even chunks -> A, odd -> B); 32 VGPR each
  bf16x8_t rsA[4], rdA[4], rsB[4], rdB[4];

  auto ldgA = [&](int t) {
#pragma unroll
    for (int i = 0; i < 4; ++i) {
      const int r = (tid >> 5) + 16 * i;
      const int s = sIdx[t * RC + r];
      const int d = dIdx[t * RC + r];
      rsA[i] = *(const bf16x8_t*)(xb + (size_t)s * DIM + cst * 8);
      rdA[i] = *(const bf16x8_t*)(xb + (size_t)d * DIM + cst * 8);
    }
  };
  auto ldgB = [&](int t) {
#pragma unroll
    for (int i = 0; i < 4; ++i) {
      const int r = (tid >> 5) + 16 * i;
      const int s = sIdx[t * RC + r];
      const int d = dIdx[t * RC + r];
      rsB[i] = *(const bf16x8_t*)(xb + (size_t)s * DIM + cst * 8);
      rdB[i] = *(const bf16x8_t*)(xb + (size_t)d * DIM + cst * 8);
    }
  };

  auto lnwr = [&](int b, bf16x8_t* rs, bf16x8_t* rd) {
#pragma unroll
    for (int i = 0; i < 4; ++i) {
      const int r = (tid >> 5) + 16 * i;
      float v[8];
#pragma unroll
      for (int j = 0; j < 8; ++j) v[j] = bf2f(rs[i][j]) + bf2f(rd[i][j]);
      float s = 0.f, ss = 0.f;
#pragma unroll
      for (int j = 0; j < 8; ++j) { s += v[j]; ss = fmaf(v[j], v[j], ss); }
#pragma unroll
      for (int off = 16; off >= 1; off >>= 1) {
        s += __shfl_xor(s, off);
        ss += __shfl_xor(ss, off);
      }
      const float mu = s * (1.0f / DIM);
      const float var = ss * (1.0f / DIM) - mu * mu;
      const float sc = rsqrtf(var + EPSV);
      bf16x8_t o;
#pragma unroll
      for (int j = 0; j < 8; ++j) o[j] = f2bf((v[j] - mu) * sc * lw[j]);
      *(bf16x8_t*)(&As[b][r * DIM + ((cst ^ (r & 7)) << 3)]) = o;
    }
  };

  auto compute = [&](int t, int b) {
    const f32x4_t zero = {0.f, 0.f, 0.f, 0.f};
    f32x4_t acc[4][2];
#pragma unroll
    for (int m = 0; m < 4; ++m) { acc[m][0] = zero; acc[m][1] = zero; }
    const short* base = As[b];
#pragma unroll
    for (int ks = 0; ks < 8; ++ks) {
      bf16x8_t af[4];
#pragma unroll
      for (int m = 0; m < 4; ++m) {
        const int row = m * 16 + rl;
        const int c = ks * 4 + kh;
        af[m] = *(const bf16x8_t*)(base + row * DIM + ((c ^ (row & 7)) << 3));
      }
#pragma unroll
      for (int m = 0; m < 4; ++m) {
        acc[m][0] = __builtin_amdgcn_mfma_f32_16x16x32_bf16(af[m], wf[0][ks], acc[m][0], 0, 0, 0);
        acc[m][1] = __builtin_amdgcn_mfma_f32_16x16x32_bf16(af[m], wf[1][ks], acc[m][1], 0, 0, 0);
      }
    }
    const int rquad = kh << 2;
#pragma unroll
    for (int n = 0; n < 2; ++n) {
      const int col = colbase + n * 16 + rl;
      float s = 0.f, q = 0.f;
#pragma unroll
      for (int m = 0; m < 4; ++m) {
        const size_t rb = (size_t)(row0 + t * RC + m * 16 + rquad) * DIM + col;
#pragma unroll
        for (int r = 0; r < 4; ++r) {
          const float f = acc[m][n][r];
          __builtin_nontemporal_store(f2bf(f), &C[rb + (size_t)r * DIM]);
          s += f;
          q = fmaf(f, f, q);
        }
      }
      if (n == 0) { st_s0 += s; st_q0 += q; }
      else        { st_s1 += s; st_q1 += q; }
    }
  };

  __syncthreads();    // idx arrays ready
  ldgA(0);            // chunk 0 -> set A
  ldgB(1);            // chunk 1 -> set B
  lnwr(0, rsA, rdA);  // counted vmcnt: waits set A only
  __syncthreads();
  for (int t = 0; t < NCH; t += 2) {
    if (t + 2 < NCH) ldgA(t + 2);        // issue ahead; flies over compute
    compute(t, 0);
    lnwr(1, rsB, rdB);                   // chunk t+1 -> buf1
    __syncthreads();
    if (t + 3 < NCH) ldgB(t + 3);
    compute(t + 1, 1);
    if (t + 2 < NCH) lnwr(0, rsA, rdA);  // chunk t+2 -> buf0
    __syncthreads();
  }

  {
    float s = st_s0, q = st_q0;
    s += __shfl_xor(s, 16); s += __shfl_xor(s, 32);
    q += __shfl_xor(q, 16); q += __shfl_xor(q, 32);
    if (lane < 16) {
      psum[(size_t)blockIdx.x * DIM + colbase + rl] = s;
      psq [(size_t)blockIdx.x * DIM + colbase + rl] = q;
    }
  }
  {
    float s = st_s1, q = st_q1;
    s += __shfl_xor(s, 16); s += __shfl_xor(s, 32);
    q += __shfl_xor(q, 16); q += __shfl_xor(q, 32);
    if (lane < 16) {
      psum[(size_t)blockIdx.x * DIM + colbase + 16 + rl] = s;
      psq [(size_t)blockIdx.x * DIM + colbase + 16 + rl] = q;
    }
  }
}

// -------- Kernel 2: BN-layer GEMM: C = relu(A*bsc+bsh) @ W^T + stats ---------
// In-place safe: block reads & writes only rows [blk*512, +512).
// bsc/bsh staged in LDS (saves 16 VGPR -> 128 total) + (512,4) => 2 blocks/CU.
extern "C" __global__ void __launch_bounds__(512, 4)
k_gemm_bn(const short* __restrict__ A, const short* __restrict__ W,
          short* __restrict__ C, float* __restrict__ psum, float* __restrict__ psq,
          const float* __restrict__ bsc, const float* __restrict__ bsh) {
  __shared__ short As[2][RC * DIM];
  __shared__ float bscS[DIM], bshS[DIM];
  const int tid = threadIdx.x;
  const int w = tid >> 6;
  const int lane = tid & 63;
  const int rl = lane & 15;
  const int kh = lane >> 4;
  const int row0 = blockIdx.x * GBM;
  const int colbase = w * 32;
  const int cst = tid & 31;

  if (tid < DIM) { bscS[tid] = bsc[tid]; bshS[tid] = bsh[tid]; }

  bf16x8_t wf[2][8];
#pragma unroll
  for (int n = 0; n < 2; ++n)
#pragma unroll
    for (int ks = 0; ks < 8; ++ks)
      wf[n][ks] = *(const bf16x8_t*)(W + (size_t)(colbase + n * 16 + rl) * DIM + ks * 32 + kh * 8);

  float st_s0 = 0.f, st_s1 = 0.f, st_q0 = 0.f, st_q1 = 0.f;

  bf16x8_t ra[4], rb[4];

  auto ldregA = [&](int t) {
#pragma unroll
    for (int i = 0; i < 4; ++i) {
      const int row = (tid + i * 512) >> 5;
      ra[i] = *(const bf16x8_t*)(A + (size_t)(row0 + t * RC + row) * DIM + cst * 8);
    }
  };
  auto ldregB = [&](int t) {
#pragma unroll
    for (int i = 0; i < 4; ++i) {
      const int row = (tid + i * 512) >> 5;
      rb[i] = *(const bf16x8_t*)(A + (size_t)(row0 + t * RC + row) * DIM + cst * 8);
    }
  };
  auto xform = [&](int b, bf16x8_t* r) {
    float cs[8], ch[8];
    const float4 c0 = *(const float4*)&bscS[cst * 8];
    const float4 c1 = *(const float4*)&bscS[cst * 8 + 4];
    const float4 h0 = *(const float4*)&bshS[cst * 8];
    const float4 h1 = *(const float4*)&bshS[cst * 8 + 4];
    cs[0]=c0.x; cs[1]=c0.y; cs[2]=c0.z; cs[3]=c0.w; cs[4]=c1.x; cs[5]=c1.y; cs[6]=c1.z; cs[7]=c1.w;
    ch[0]=h0.x; ch[1]=h0.y; ch[2]=h0.z; ch[3]=h0.w; ch[4]=h1.x; ch[5]=h1.y; ch[6]=h1.z; ch[7]=h1.w;
#pragma unroll
    for (int i = 0; i < 4; ++i) {
      const int row = (tid + i * 512) >> 5;
      bf16x8_t v = r[i];
      bf16x8_t o;
#pragma unroll
      for (int j = 0; j < 8; ++j)
        o[j] = f2bf(fmaxf(fmaf(bf2f(v[j]), cs[j], ch[j]), 0.0f));
      *(bf16x8_t*)(&As[b][row * DIM + ((cst ^ (row & 7)) << 3)]) = o;
    }
  };

  auto compute = [&](int t, int b) {
    const f32x4_t zero = {0.f, 0.f, 0.f, 0.f};
    f32x4_t acc[4][2];
#pragma unroll
    for (int m = 0; m < 4; ++m) { acc[m][0] = zero; acc[m][1] = zero; }
    const short* base = As[b];
#pragma unroll
    for (int ks = 0; ks < 8; ++ks) {
      bf16x8_t af[4];
#pragma unroll
      for (int m = 0; m < 4; ++m) {
        const int row = m * 16 + rl;
        const int c = ks * 4 + kh;
        af[m] = *(const bf16x8_t*)(base + row * DIM + ((c ^ (row & 7)) << 3));
      }
#pragma unroll
      for (int m = 0; m < 4; ++m) {
        acc[m][0] = __builtin_amdgcn_mfma_f32_16x16x32_bf16(af[m], wf[0][ks], acc[m][0], 0, 0, 0);
        acc[m][1] = __builtin_amdgcn_mfma_f32_16x16x32_bf16(af[m], wf[1][ks], acc[m][1], 0, 0, 0);
      }
    }
    const int rquad = kh << 2;
#pragma unroll
    for (int n = 0; n < 2; ++n) {
      const int col = colbase + n * 16 + rl;
      float s = 0.f, q = 0.f;
#pragma unroll
      for (int m = 0; m < 4; ++m) {
        const size_t rb2 = (size_t)(row0 + t * RC + m * 16 + rquad) * DIM + col;
#pragma unroll
        for (int r = 0; r < 4; ++r) {
          const float f = acc[m][n][r];
          C[rb2 + (size_t)r * DIM] = f2bf(f);
          s += f;
          q = fmaf(f, f, q);
        }
      }
      if (n == 0) { st_s0 += s; st_q0 += q; }
      else        { st_s1 += s; st_q1 += q; }
    }
  };

  __syncthreads();   // bscS/bshS ready
  ldregA(0);
  ldregB(1);
  xform(0, ra);      // counted vmcnt: waits A-set only
  __syncthreads();
  for (int t = 0; t < NCH; t += 2) {
    if (t + 2 < NCH) ldregA(t + 2);
    compute(t, 0);
    xform(1, rb);
    __syncthreads();
    if (t + 3 < NCH) ldregB(t + 3);
    compute(t + 1, 1);
    if (t + 2 < NCH) xform(0, ra);
    __syncthreads();
  }

  {
    float s = st_s0, q = st_q0;
    s += __shfl_xor(s, 16); s += __shfl_xor(s, 32);
    q += __shfl_xor(q, 16); q += __shfl_xor(q, 32);
    if (lane < 16) {
      psum[(size_t)blockIdx.x * DIM + colbase + rl] = s;
      psq [(size_t)blockIdx.x * DIM + colbase + rl] = q;
    }
  }
  {
    float s = st_s1, q = st_q1;
    s += __shfl_xor(s, 16); s += __shfl_xor(s, 32);
    q += __shfl_xor(q, 16); q += __shfl_xor(q, 32);
    if (lane < 16) {
      psum[(size_t)blockIdx.x * DIM + colbase + 16 + rl] = s;
      psq [(size_t)blockIdx.x * DIM + colbase + 16 + rl] = q;
    }
  }
}

// ---------------- Kernel 3: finalize batch stats -> scale/shift --------------
extern "C" __global__ void __launch_bounds__(64)
k_stats(const float* __restrict__ psum, const float* __restrict__ psq,
        const float* __restrict__ gamma, const float* __restrict__ beta,
        float* __restrict__ sc, float* __restrict__ sh, int nblk) {
  const int c = blockIdx.x;
  const int lane = threadIdx.x;
  float s = 0.0f, q = 0.0f;
  for (int b = lane; b < nblk; b += 64) {
    s += psum[(size_t)b * DIM + c];
    q += psq[(size_t)b * DIM + c];
  }
#pragma unroll
  for (int off = 32; off >= 1; off >>= 1) {
    s += __shfl_xor(s, off);
    q += __shfl_xor(q, off);
  }
  if (lane == 0) {
    const float inv = 1.0f / NEDGE;
    const float mu = s * inv;
    const float var = q * inv - mu * mu;
    const float scale = rsqrtf(var + EPSV) * gamma[c];
    sc[c] = scale;
    sh[c] = beta[c] - mu * scale;
  }
}

// ---------------- Kernel 4: logits = relu(bn3(h3)) . w_out ------------------
extern "C" __global__ void __launch_bounds__(256)
k_head(const short* __restrict__ h3, const float* __restrict__ sc,
       const float* __restrict__ sh, const float* __restrict__ wout,
       float* __restrict__ out) {
  const int e = (blockIdx.x << 3) + (threadIdx.x >> 5);
  const int g = threadIdx.x & 31;
  const int c = g * 8;
  const bf16x8_t v = *(const bf16x8_t*)(h3 + (size_t)e * DIM + c);
  float acc = 0.f;
#pragma unroll
  for (int j = 0; j < 8; ++j)
    acc += fmaxf(fmaf(bf2f(v[j]), sc[c + j], sh[c + j]), 0.0f) * wout[c + j];
#pragma unroll
  for (int off = 16; off >= 1; off >>= 1) acc += __shfl_xor(acc, off);
  if (g == 0) out[e] = acc;
}

extern "C" void kernel_launch(void* const* d_in, const int* in_sizes, int n_in,
                              void* d_out, int out_size, void* d_ws, size_t ws_size,
                              hipStream_t stream) {
  const float* x = (const float*)d_in[0];
  const int* ei = (const int*)d_in[1];
  const float* lnw = (const float*)d_in[2];
  const float* Ws = (const float*)d_in[3];
  const float* gammas = (const float*)d_in[4];
  const float* betas = (const float*)d_in[5];
  const float* wout = (const float*)d_in[6];
  float* out = (float*)d_out;

  // Workspace (~155 MB): h 128MB | Wb 384KB | psum 512KB | psq 512KB | bn 6KB | xb 25.6MB
  char* ws = (char*)d_ws;
  const size_t HBYTES = (size_t)NEDGE * DIM * 2;
  short* h = (short*)ws;
  short* Wb = (short*)(ws + HBYTES);
  char* p = ws + HBYTES + (size_t)NLAYER * DIM * DIM * 2;
  float* psum = (float*)p;
  float* psq = psum + (size_t)GEMM_GRID * DIM;
  float* bnsc = psq + (size_t)GEMM_GRID * DIM;
  float* bnsh = bnsc + NLAYER * DIM;
  short* xb = (short*)(bnsh + NLAYER * DIM);

  k_cvt<<<(NLAYER * DIM * DIM + 255) / 256, 256, 0, stream>>>(Ws, Wb, NLAYER * DIM * DIM);
  k_cvt_x<<<(NNODE * DIM / 8 + 255) / 256, 256, 0, stream>>>(x, xb, NNODE * DIM / 8);

  // layer 1: fused gather+LN+GEMM
  k_gemm1f<<<GEMM_GRID, 512, 0, stream>>>(xb, ei, lnw, Wb, h, psum, psq);
  k_stats<<<DIM, 64, 0, stream>>>(psum, psq, gammas, betas, bnsc, bnsh, GEMM_GRID);

  for (int l = 1; l < NLAYER; ++l) {
    k_gemm_bn<<<GEMM_GRID, 512, 0, stream>>>(h, Wb + (size_t)l * DIM * DIM, h,
                                             psum, psq,
                                             bnsc + (size_t)(l - 1) * DIM,
                                             bnsh + (size_t)(l - 1) * DIM);
    k_stats<<<DIM, 64, 0, stream>>>(psum, psq, gammas + (size_t)l * DIM,
                                    betas + (size_t)l * DIM,
                                    bnsc + (size_t)l * DIM, bnsh + (size_t)l * DIM,
                                    GEMM_GRID);
  }
  k_head<<<NEDGE / 8, 256, 0, stream>>>(h, bnsc + (size_t)(NLAYER - 1) * DIM,
                                        bnsh + (size_t)(NLAYER - 1) * DIM, wout, out);
}

// Round 9
// 321.740 us; speedup vs baseline: 1.6162x; 1.6162x over previous
//
#include <hip/hip_runtime.h>
#include <hip/hip_bf16.h>

#define NEDGE 262144
#define DIM 256
#define NNODE 50000
#define NLAYER 3
#define EPSV 1e-5f

// layer-1 fused kernel geometry
#define GBM1 256                  // rows per block
#define RC1 32                    // rows per chunk
#define NCH1 (GBM1 / RC1)         // 8 chunks
#define GRID1 (NEDGE / GBM1)      // 1024 blocks

// BN-layer GEMM geometry (R5-proven)
#define GBM 512
#define RC 64
#define NCH (GBM / RC)
#define GEMM_GRID (NEDGE / GBM)

typedef __attribute__((ext_vector_type(8))) short bf16x8_t;
typedef __attribute__((ext_vector_type(4))) short bf16x4_t;
typedef __attribute__((ext_vector_type(4))) float f32x4_t;

__device__ __forceinline__ float bf2f(short s) {
  unsigned u = ((unsigned)(unsigned short)s) << 16;
  return __builtin_bit_cast(float, u);
}
__device__ __forceinline__ short f2bf(float f) {
  __hip_bfloat16 h = __float2bfloat16(f);
  return __builtin_bit_cast(short, h);
}

// ---------------- Kernel 0a: convert Ws (fp32) -> bf16 (layers 2,3) ---------
extern "C" __global__ void __launch_bounds__(256)
k_cvt(const float* __restrict__ src, short* __restrict__ dst, int n) {
  int i = blockIdx.x * 256 + threadIdx.x;
  if (i < n) dst[i] = f2bf(src[i]);
}

// ---------------- Kernel 0b: layer-1 W' = lnw*W (bf16) and u[c] = sum_k lnw*W
extern "C" __global__ void __launch_bounds__(64)
k_cvtw(const float* __restrict__ W, const float* __restrict__ lnw,
       short* __restrict__ Wp, float* __restrict__ u) {
  const int c = blockIdx.x;
  const int j = threadIdx.x;
  const float4 wv = *(const float4*)(W + (size_t)c * DIM + j * 4);
  const float4 lv = *(const float4*)(lnw + j * 4);
  const float p0 = wv.x * lv.x, p1 = wv.y * lv.y, p2 = wv.z * lv.z, p3 = wv.w * lv.w;
  bf16x4_t o;
  o[0] = f2bf(p0); o[1] = f2bf(p1); o[2] = f2bf(p2); o[3] = f2bf(p3);
  *(bf16x4_t*)(Wp + (size_t)c * DIM + j * 4) = o;
  float s = p0 + p1 + p2 + p3;
#pragma unroll
  for (int off = 32; off >= 1; off >>= 1) s += __shfl_xor(s, off);
  if (j == 0) u[c] = s;
}

// ---------------- Kernel 0c: convert x (fp32) -> bf16 -----------------------
extern "C" __global__ void __launch_bounds__(256)
k_cvt_x(const float* __restrict__ src, short* __restrict__ dst, int n8) {
  int i = blockIdx.x * 256 + threadIdx.x;
  if (i >= n8) return;
  const float4 a = *(const float4*)(src + (size_t)i * 8);
  const float4 b = *(const float4*)(src + (size_t)i * 8 + 4);
  bf16x8_t o;
  o[0] = f2bf(a.x); o[1] = f2bf(a.y); o[2] = f2bf(a.z); o[3] = f2bf(a.w);
  o[4] = f2bf(b.x); o[5] = f2bf(b.y); o[6] = f2bf(b.z); o[7] = f2bf(b.w);
  *(bf16x8_t*)(dst + (size_t)i * 8) = o;
}

// ---------------- Kernel 0d: per-node rowsum / rowsumsq of xb ---------------
extern "C" __global__ void __launch_bounds__(256)
k_prep(const short* __restrict__ xb, float2* __restrict__ rstat, int nnode) {
  const int node = blockIdx.x * 8 + (threadIdx.x >> 5);
  if (node >= nnode) return;
  const int g = threadIdx.x & 31;
  const bf16x8_t v = *(const bf16x8_t*)(xb + (size_t)node * DIM + g * 8);
  float s = 0.f, q = 0.f;
#pragma unroll
  for (int j = 0; j < 8; ++j) { const float f = bf2f(v[j]); s += f; q = fmaf(f, f, q); }
#pragma unroll
  for (int off = 16; off >= 1; off >>= 1) { s += __shfl_xor(s, off); q += __shfl_xor(q, off); }
  if (g == 0) rstat[node] = make_float2(s, q);
}

// ======== Kernel 1: fused gather+LN+GEMM1 via LN-folding =====================
// C[e] = inv_e * ( (xs+xd) @ W'^T  -  mu_e * u ),   W' = lnw*W  (precomputed)
// mu_e, inv_e from per-node rowsums + cross-dot (extra MFMA, diag extract).
// Raw s/d tiles staged async via global_load_lds (pre-swizzled source).
// Swapped-operand MFMA -> lane holds 4 contiguous cols -> 8B stores.
extern "C" __global__ void __launch_bounds__(512)
k_gemm1f(const short* __restrict__ xb, const int* __restrict__ ei,
         const short* __restrict__ Wp, const float* __restrict__ u,
         const float2* __restrict__ rstat, short* __restrict__ C,
         float* __restrict__ psum, float* __restrict__ psq) {
  __shared__ short As[2][2 * RC1 * DIM];  // [buf][ s 32x256 | d 32x256 ] = 2x32KB
  __shared__ int sIdx[GBM1], dIdx[GBM1];
  __shared__ float uS[DIM];
  const int tid = threadIdx.x;
  const int w = tid >> 6;
  const int lane = tid & 63;
  const int rl = lane & 15;
  const int kh = lane >> 4;
  const int row0 = blockIdx.x * GBM1;
  const int cb = w * 32;

  if (tid < GBM1) { sIdx[tid] = ei[row0 + tid]; dIdx[tid] = ei[NEDGE + row0 + tid]; }
  if (tid < DIM) uS[tid] = u[tid];

  // W' fragments: wf[n] holds W'[cb+n*16+rl][ks*32+kh*8 ..+8]
  bf16x8_t wf[2][8];
#pragma unroll
  for (int n = 0; n < 2; ++n)
#pragma unroll
    for (int ks = 0; ks < 8; ++ks)
      wf[n][ks] = *(const bf16x8_t*)(Wp + (size_t)(cb + n * 16 + rl) * DIM + ks * 32 + kh * 8);

  float st_s[2][4], st_q[2][4];
#pragma unroll
  for (int n = 0; n < 2; ++n)
#pragma unroll
    for (int r = 0; r < 4; ++r) { st_s[n][r] = 0.f; st_q[n][r] = 0.f; }

  // stage chunk t into buf b: 64 row-slots (0..31 = s rows, 32..63 = d rows),
  // wave w owns slots [8w, 8w+8): 4 instrs x 2 rows (64 lanes x 16B = 1KB).
  auto stage = [&](int t, int b) {
#pragma unroll
    for (int i = 0; i < 4; ++i) {
      const int slot0 = w * 8 + 2 * i;
      const int slot = slot0 + (lane >> 5);
      const int rr = slot & 31;
      const int nd = (slot < 32) ? sIdx[t * RC1 + rr] : dIdx[t * RC1 + rr];
      const short* gp = xb + (size_t)nd * DIM + (((lane & 31) ^ (rr & 7)) << 3);
      short* lp = &As[b][slot0 * DIM];
      __builtin_amdgcn_global_load_lds(
          (const __attribute__((address_space(1))) unsigned int*)gp,
          (__attribute__((address_space(3))) unsigned int*)lp, 16, 0, 0);
    }
  };

  auto compute = [&](int t, int b) {
    const f32x4_t zero = {0.f, 0.f, 0.f, 0.f};
    f32x4_t acc[2][2], accd[2];
#pragma unroll
    for (int m = 0; m < 2; ++m) { acc[m][0] = zero; acc[m][1] = zero; accd[m] = zero; }
    // per-row node stats (L2-resident, issued early, used in epilogue)
    float2 rsS[2], rsD[2];
#pragma unroll
    for (int m = 0; m < 2; ++m) {
      const int rr = t * RC1 + m * 16 + rl;
      rsS[m] = rstat[sIdx[rr]];
      rsD[m] = rstat[dIdx[rr]];
    }
    const short* base = As[b];
#pragma unroll
    for (int ks = 0; ks < 8; ++ks) {
      bf16x8_t sf[2], df[2];
#pragma unroll
      for (int m = 0; m < 2; ++m) {
        const int rr = m * 16 + rl;
        const int ch = ((ks * 4 + kh) ^ (rr & 7)) << 3;  // short offset
        sf[m] = *(const bf16x8_t*)(base + rr * DIM + ch);
        df[m] = *(const bf16x8_t*)(base + (32 + rr) * DIM + ch);
      }
#pragma unroll
      for (int m = 0; m < 2; ++m) {
#pragma unroll
        for (int n = 0; n < 2; ++n) {
          acc[m][n] = __builtin_amdgcn_mfma_f32_16x16x32_bf16(wf[n][ks], sf[m], acc[m][n], 0, 0, 0);
          acc[m][n] = __builtin_amdgcn_mfma_f32_16x16x32_bf16(wf[n][ks], df[m], acc[m][n], 0, 0, 0);
        }
        accd[m] = __builtin_amdgcn_mfma_f32_16x16x32_bf16(sf[m], df[m], accd[m], 0, 0, 0);
      }
    }
    // epilogue: diag extract -> row stats -> folded LN affine -> 8B stores
#pragma unroll
    for (int m = 0; m < 2; ++m) {
      // owner lane of diag(rl) holds it at reg rl&3; select via 2-level cndmask
      const float dsel = (lane & 2) ? ((lane & 1) ? accd[m][3] : accd[m][2])
                                    : ((lane & 1) ? accd[m][1] : accd[m][0]);
      const float dot = __shfl(dsel, ((rl >> 2) << 4) | rl, 64);
      const float S = rsS[m].x + rsD[m].x;
      const float Q = rsS[m].y + rsD[m].y + 2.f * dot;
      const float mu = S * (1.0f / DIM);
      const float inv = rsqrtf(Q * (1.0f / DIM) - mu * mu + EPSV);
      const int grow = row0 + t * RC1 + m * 16 + rl;
#pragma unroll
      for (int n = 0; n < 2; ++n) {
        const f32x4_t uv = *(const f32x4_t*)&uS[cb + n * 16 + kh * 4];
        bf16x4_t o;
#pragma unroll
        for (int r = 0; r < 4; ++r) {
          const float v = (acc[m][n][r] - mu * uv[r]) * inv;
          o[r] = f2bf(v);
          st_s[n][r] += v;
          st_q[n][r] = fmaf(v, v, st_q[n][r]);
        }
        *(bf16x4_t*)(C + (size_t)grow * DIM + cb + n * 16 + kh * 4) = o;
      }
    }
  };

  __syncthreads();  // sIdx/dIdx/uS ready
  stage(0, 0);
  for (int t = 0; t < NCH1; ++t) {
    __syncthreads();  // drains stage(t) (vmcnt0) + prior lgkm
    if (t + 1 < NCH1) stage(t + 1, (t + 1) & 1);
    compute(t, t & 1);
  }

  // block column stats: lanes with same kh share cols across rl -> reduce rl
#pragma unroll
  for (int n = 0; n < 2; ++n)
#pragma unroll
    for (int r = 0; r < 4; ++r) {
#pragma unroll
      for (int off = 8; off >= 1; off >>= 1) {
        st_s[n][r] += __shfl_xor(st_s[n][r], off);
        st_q[n][r] += __shfl_xor(st_q[n][r], off);
      }
    }
  if (rl == 0) {
#pragma unroll
    for (int n = 0; n < 2; ++n)
#pragma unroll
      for (int r = 0; r < 4; ++r) {
        const int col = cb + n * 16 + kh * 4 + r;
        psum[(size_t)blockIdx.x * DIM + col] = st_s[n][r];
        psq [(size_t)blockIdx.x * DIM + col] = st_q[n][r];
      }
  }
}

// -------- Kernel 2: BN-layer GEMM (R5-proven, exact): C = relu(A*sc+sh)@W^T --
extern "C" __global__ void __launch_bounds__(512, 2)
k_gemm_bn(const short* __restrict__ A, const short* __restrict__ W,
          short* __restrict__ C, float* __restrict__ psum, float* __restrict__ psq,
          const float* __restrict__ bsc, const float* __restrict__ bsh) {
  __shared__ short As[2][RC * DIM];
  const int tid = threadIdx.x;
  const int w = tid >> 6;
  const int lane = tid & 63;
  const int rl = lane & 15;
  const int kh = lane >> 4;
  const int row0 = blockIdx.x * GBM;
  const int colbase = w * 32;

  bf16x8_t wf[2][8];
#pragma unroll
  for (int n = 0; n < 2; ++n)
#pragma unroll
    for (int ks = 0; ks < 8; ++ks)
      wf[n][ks] = *(const bf16x8_t*)(W + (size_t)(colbase + n * 16 + rl) * DIM + ks * 32 + kh * 8);

  const int cst = tid & 31;
  float sc0[8], sh0[8];
#pragma unroll
  for (int j = 0; j < 8; ++j) {
    sc0[j] = bsc[cst * 8 + j];
    sh0[j] = bsh[cst * 8 + j];
  }

  float st_s0 = 0.f, st_s1 = 0.f, st_q0 = 0.f, st_q1 = 0.f;

  bf16x8_t ra[4], rb[4];
  auto ldregA = [&](int t) {
#pragma unroll
    for (int i = 0; i < 4; ++i) {
      const int row = (tid + i * 512) >> 5;
      ra[i] = *(const bf16x8_t*)(A + (size_t)(row0 + t * RC + row) * DIM + cst * 8);
    }
  };
  auto ldregB = [&](int t) {
#pragma unroll
    for (int i = 0; i < 4; ++i) {
      const int row = (tid + i * 512) >> 5;
      rb[i] = *(const bf16x8_t*)(A + (size_t)(row0 + t * RC + row) * DIM + cst * 8);
    }
  };
  auto xform = [&](int b, bf16x8_t* r) {
#pragma unroll
    for (int i = 0; i < 4; ++i) {
      const int row = (tid + i * 512) >> 5;
      bf16x8_t v = r[i];
      bf16x8_t o;
#pragma unroll
      for (int j = 0; j < 8; ++j)
        o[j] = f2bf(fmaxf(fmaf(bf2f(v[j]), sc0[j], sh0[j]), 0.0f));
      *(bf16x8_t*)(&As[b][row * DIM + ((cst ^ (row & 7)) << 3)]) = o;
    }
  };

  auto compute = [&](int t, int b) {
    const f32x4_t zero = {0.f, 0.f, 0.f, 0.f};
    f32x4_t acc[4][2];
#pragma unroll
    for (int m = 0; m < 4; ++m) { acc[m][0] = zero; acc[m][1] = zero; }
    const short* base = As[b];
#pragma unroll
    for (int ks = 0; ks < 8; ++ks) {
      bf16x8_t af[4];
#pragma unroll
      for (int m = 0; m < 4; ++m) {
        const int row = m * 16 + rl;
        const int c = ks * 4 + kh;
        af[m] = *(const bf16x8_t*)(base + row * DIM + ((c ^ (row & 7)) << 3));
      }
#pragma unroll
      for (int m = 0; m < 4; ++m) {
        acc[m][0] = __builtin_amdgcn_mfma_f32_16x16x32_bf16(af[m], wf[0][ks], acc[m][0], 0, 0, 0);
        acc[m][1] = __builtin_amdgcn_mfma_f32_16x16x32_bf16(af[m], wf[1][ks], acc[m][1], 0, 0, 0);
      }
    }
    const int rquad = kh << 2;
#pragma unroll
    for (int n = 0; n < 2; ++n) {
      const int col = colbase + n * 16 + rl;
      float s = 0.f, q = 0.f;
#pragma unroll
      for (int m = 0; m < 4; ++m) {
        const size_t rb2 = (size_t)(row0 + t * RC + m * 16 + rquad) * DIM + col;
#pragma unroll
        for (int r = 0; r < 4; ++r) {
          const float f = acc[m][n][r];
          C[rb2 + (size_t)r * DIM] = f2bf(f);
          s += f;
          q = fmaf(f, f, q);
        }
      }
      if (n == 0) { st_s0 += s; st_q0 += q; }
      else        { st_s1 += s; st_q1 += q; }
    }
  };

  ldregA(0);
  xform(0, ra);
  ldregB(1);
  __syncthreads();
  for (int t = 0; t < NCH; t += 2) {
    if (t + 2 < NCH) ldregA(t + 2);
    compute(t, 0);
    xform(1, rb);
    __syncthreads();
    if (t + 3 < NCH) ldregB(t + 3);
    compute(t + 1, 1);
    if (t + 2 < NCH) xform(0, ra);
    __syncthreads();
  }

  {
    float s = st_s0, q = st_q0;
    s += __shfl_xor(s, 16); s += __shfl_xor(s, 32);
    q += __shfl_xor(q, 16); q += __shfl_xor(q, 32);
    if (lane < 16) {
      psum[(size_t)blockIdx.x * DIM + colbase + rl] = s;
      psq [(size_t)blockIdx.x * DIM + colbase + rl] = q;
    }
  }
  {
    float s = st_s1, q = st_q1;
    s += __shfl_xor(s, 16); s += __shfl_xor(s, 32);
    q += __shfl_xor(q, 16); q += __shfl_xor(q, 32);
    if (lane < 16) {
      psum[(size_t)blockIdx.x * DIM + colbase + 16 + rl] = s;
      psq [(size_t)blockIdx.x * DIM + colbase + 16 + rl] = q;
    }
  }
}

// ---------------- Kernel 3: finalize batch stats -> scale/shift --------------
extern "C" __global__ void __launch_bounds__(64)
k_stats(const float* __restrict__ psum, const float* __restrict__ psq,
        const float* __restrict__ gamma, const float* __restrict__ beta,
        float* __restrict__ sc, float* __restrict__ sh, int nblk) {
  const int c = blockIdx.x;
  const int lane = threadIdx.x;
  float s = 0.0f, q = 0.0f;
  for (int b = lane; b < nblk; b += 64) {
    s += psum[(size_t)b * DIM + c];
    q += psq[(size_t)b * DIM + c];
  }
#pragma unroll
  for (int off = 32; off >= 1; off >>= 1) {
    s += __shfl_xor(s, off);
    q += __shfl_xor(q, off);
  }
  if (lane == 0) {
    const float inv = 1.0f / NEDGE;
    const float mu = s * inv;
    const float var = q * inv - mu * mu;
    const float scale = rsqrtf(var + EPSV) * gamma[c];
    sc[c] = scale;
    sh[c] = beta[c] - mu * scale;
  }
}

// ---------------- Kernel 4: logits = relu(bn3(h3)) . w_out ------------------
extern "C" __global__ void __launch_bounds__(256)
k_head(const short* __restrict__ h3, const float* __restrict__ sc,
       const float* __restrict__ sh, const float* __restrict__ wout,
       float* __restrict__ out) {
  const int e = (blockIdx.x << 3) + (threadIdx.x >> 5);
  const int g = threadIdx.x & 31;
  const int c = g * 8;
  const bf16x8_t v = *(const bf16x8_t*)(h3 + (size_t)e * DIM + c);
  float acc = 0.f;
#pragma unroll
  for (int j = 0; j < 8; ++j)
    acc += fmaxf(fmaf(bf2f(v[j]), sc[c + j], sh[c + j]), 0.0f) * wout[c + j];
#pragma unroll
  for (int off = 16; off >= 1; off >>= 1) acc += __shfl_xor(acc, off);
  if (g == 0) out[e] = acc;
}

extern "C" void kernel_launch(void* const* d_in, const int* in_sizes, int n_in,
                              void* d_out, int out_size, void* d_ws, size_t ws_size,
                              hipStream_t stream) {
  const float* x = (const float*)d_in[0];
  const int* ei = (const int*)d_in[1];
  const float* lnw = (const float*)d_in[2];
  const float* Ws = (const float*)d_in[3];
  const float* gammas = (const float*)d_in[4];
  const float* betas = (const float*)d_in[5];
  const float* wout = (const float*)d_in[6];
  float* out = (float*)d_out;

  // Workspace (~163 MB): h 128MB | xb 25.6MB | Wb 384KB | u 1KB | rstat 400KB
  //                      | psum 1MB | psq 1MB | bn 6KB
  char* ws = (char*)d_ws;
  const size_t HBYTES = (size_t)NEDGE * DIM * 2;
  short* h = (short*)ws;
  short* xb = (short*)(ws + HBYTES);
  short* Wb = (short*)(ws + HBYTES + (size_t)NNODE * DIM * 2);
  char* p = (char*)Wb + (size_t)NLAYER * DIM * DIM * 2;
  float* u = (float*)p;
  float2* rstat = (float2*)(p + 1024);
  float* psum = (float*)(p + 1024 + (size_t)NNODE * 8);
  float* psq = psum + (size_t)GRID1 * DIM;
  float* bnsc = psq + (size_t)GRID1 * DIM;
  float* bnsh = bnsc + NLAYER * DIM;

  // prep: W' + u (layer 1), plain bf16 W (layers 2,3), xb, per-node stats
  k_cvtw<<<DIM, 64, 0, stream>>>(Ws, lnw, Wb, u);
  k_cvt<<<(2 * DIM * DIM + 255) / 256, 256, 0, stream>>>(
      Ws + (size_t)DIM * DIM, Wb + (size_t)DIM * DIM, 2 * DIM * DIM);
  k_cvt_x<<<(NNODE * DIM / 8 + 255) / 256, 256, 0, stream>>>(x, xb, NNODE * DIM / 8);
  k_prep<<<(NNODE + 7) / 8, 256, 0, stream>>>(xb, rstat, NNODE);

  // layer 1: fused gather + folded-LN + GEMM
  k_gemm1f<<<GRID1, 512, 0, stream>>>(xb, ei, Wb, u, rstat, h, psum, psq);
  k_stats<<<DIM, 64, 0, stream>>>(psum, psq, gammas, betas, bnsc, bnsh, GRID1);

  for (int l = 1; l < NLAYER; ++l) {
    k_gemm_bn<<<GEMM_GRID, 512, 0, stream>>>(h, Wb + (size_t)l * DIM * DIM, h,
                                             psum, psq,
                                             bnsc + (size_t)(l - 1) * DIM,
                                             bnsh + (size_t)(l - 1) * DIM);
    k_stats<<<DIM, 64, 0, stream>>>(psum, psq, gammas + (size_t)l * DIM,
                                    betas + (size_t)l * DIM,
                                    bnsc + (size_t)l * DIM, bnsh + (size_t)l * DIM,
                                    GEMM_GRID);
  }
  k_head<<<NEDGE / 8, 256, 0, stream>>>(h, bnsc + (size_t)(NLAYER - 1) * DIM,
                                        bnsh + (size_t)(NLAYER - 1) * DIM, wout, out);
}